// Round 1
// baseline (713.739 us; speedup 1.0000x reference)
//
#include <hip/hip_runtime.h>

#define KDIM 4096      // widened dim (n*C)
#define K4   1024      // KDIM/4 (float4 units)
#define NS   4         // streams
#define TB   8         // tokens per block
#define NROWS 24       // 16 res + 4 pre + 4 post

constexpr float kLOG2E = 1.44269504088896340736f;
constexpr float kLN2   = 0.69314718055994530942f;
constexpr float kEPS   = 1.1920929e-07f;   // finfo(float32).eps
constexpr float kTAUI  = 10.0f;            // 1/tau

__global__ __launch_bounds__(256) void dynmhc_fused(
    const float* __restrict__ x,
    const float* __restrict__ Wres,
    const float* __restrict__ Wpre,
    const float* __restrict__ Wpost,
    const float* __restrict__ Hres_b,
    const float* __restrict__ Hpre_b,
    const float* __restrict__ Hpost_b,
    const float* __restrict__ gate,
    float* __restrict__ out)
{
    const int tid  = threadIdx.x;
    const int wave = tid >> 6;
    const int lane = tid & 63;
    const size_t t0 = (size_t)blockIdx.x * TB;

    __shared__ float s_dots[NROWS][TB];
    __shared__ float s_ssq[TB];
    __shared__ float s_Hres[TB][NS][NS];
    __shared__ float s_Hpre[TB][NS];
    __shared__ float s_Hpost[TB][NS];

    const float4* x4 = reinterpret_cast<const float4*>(x);

    // ---------------- phase 1: 24 dots + ssq per token ----------------
    // wave w owns rows 6w..6w+5 (row-split so no cross-wave reduction)
    const float* wrow[6];
#pragma unroll
    for (int r = 0; r < 6; ++r) {
        const int rg = wave * 6 + r;
        const float* p;
        if (rg < 16)      p = Wres  + (size_t)rg * KDIM;
        else if (rg < 20) p = Wpre  + (size_t)(rg - 16) * KDIM;
        else              p = Wpost + (size_t)(rg - 20) * KDIM;
        wrow[r] = p;
    }

    float acc[6][TB];
#pragma unroll
    for (int r = 0; r < 6; ++r)
#pragma unroll
        for (int t = 0; t < TB; ++t) acc[r][t] = 0.0f;
    float ssq[TB];
#pragma unroll
    for (int t = 0; t < TB; ++t) ssq[t] = 0.0f;

    for (int it = 0; it < K4 / 64; ++it) {   // 16 iterations
        const int k4 = it * 64 + lane;       // float4 index, coalesced per wave
        float4 wv[6];
#pragma unroll
        for (int r = 0; r < 6; ++r)
            wv[r] = reinterpret_cast<const float4*>(wrow[r])[k4];
#pragma unroll
        for (int t = 0; t < TB; ++t) {
            const float4 xv = x4[(t0 + t) * K4 + k4];
#pragma unroll
            for (int r = 0; r < 6; ++r) {
                float a = acc[r][t];
                a = fmaf(wv[r].x, xv.x, a);
                a = fmaf(wv[r].y, xv.y, a);
                a = fmaf(wv[r].z, xv.z, a);
                a = fmaf(wv[r].w, xv.w, a);
                acc[r][t] = a;
            }
            if (wave == 0) {
                float q = ssq[t];
                q = fmaf(xv.x, xv.x, q);
                q = fmaf(xv.y, xv.y, q);
                q = fmaf(xv.z, xv.z, q);
                q = fmaf(xv.w, xv.w, q);
                ssq[t] = q;
            }
        }
    }

#pragma unroll
    for (int r = 0; r < 6; ++r)
#pragma unroll
        for (int t = 0; t < TB; ++t) {
            float v = acc[r][t];
#pragma unroll
            for (int off = 32; off >= 1; off >>= 1)
                v += __shfl_xor(v, off, 64);
            if (lane == 0) s_dots[wave * 6 + r][t] = v;
        }
    if (wave == 0) {
#pragma unroll
        for (int t = 0; t < TB; ++t) {
            float v = ssq[t];
#pragma unroll
            for (int off = 32; off >= 1; off >>= 1)
                v += __shfl_xor(v, off, 64);
            if (lane == 0) s_ssq[t] = v;
        }
    }
    __syncthreads();

    // ---------------- phase 2: Sinkhorn + softmaxes ----------------
    // wave w handles tokens 2w (lanes 0-15) and 2w+1 (lanes 16-31);
    // lane l16 = i*4+j holds Z[i][j]; row-LSE via xor 1,2; col-LSE via xor 4,8.
    if (lane < 32) {
        const int tok = wave * 2 + (lane >> 4);
        const int l16 = lane & 15;
        const int i = l16 >> 2;
        const int j = l16 & 3;
        const float s = rsqrtf(s_ssq[tok] * (1.0f / KDIM) + kEPS);
        const float Z = (Hres_b[l16] + s * s_dots[l16][tok]) * kTAUI;
        float u = 0.0f, v = 0.0f;
        for (int itr = 0; itr < 50; ++itr) {
            float tt = Z + v;
            float m = fmaxf(tt, __shfl_xor(tt, 1, 64));
            m = fmaxf(m, __shfl_xor(m, 2, 64));
            float e = exp2f((tt - m) * kLOG2E);
            e += __shfl_xor(e, 1, 64);
            e += __shfl_xor(e, 2, 64);
            u = -fmaf(log2f(e), kLN2, m);
            tt = Z + u;
            m = fmaxf(tt, __shfl_xor(tt, 4, 64));
            m = fmaxf(m, __shfl_xor(m, 8, 64));
            e = exp2f((tt - m) * kLOG2E);
            e += __shfl_xor(e, 4, 64);
            e += __shfl_xor(e, 8, 64);
            v = -fmaf(log2f(e), kLN2, m);
        }
        const float g = 1.0f / (1.0f + expf(-gate[0]));
        const float P = exp2f((Z + u + v) * kLOG2E);
        s_Hres[tok][i][j] = (1.0f - g) * ((i == j) ? 1.0f : 0.0f) + g * P;

        if (i == 0) {          // lanes j=0..3 compute H_pre softmax
            const float lp = Hpre_b[j] + s * s_dots[16 + j][tok];
            float m2 = fmaxf(lp, __shfl_xor(lp, 1, 64));
            m2 = fmaxf(m2, __shfl_xor(m2, 2, 64));
            const float e2 = exp2f((lp - m2) * kLOG2E);
            float se = e2 + __shfl_xor(e2, 1, 64);
            se += __shfl_xor(se, 2, 64);
            s_Hpre[tok][j] = e2 / se;
        } else if (i == 1) {   // lanes compute H_post softmax
            const float lp = Hpost_b[j] + s * s_dots[20 + j][tok];
            float m2 = fmaxf(lp, __shfl_xor(lp, 1, 64));
            m2 = fmaxf(m2, __shfl_xor(m2, 2, 64));
            const float e2 = exp2f((lp - m2) * kLOG2E);
            float se = e2 + __shfl_xor(e2, 1, 64);
            se += __shfl_xor(se, 2, 64);
            s_Hpost[tok][j] = e2 / se;
        }
    }
    __syncthreads();

    // ---------------- phase 3: output mix ----------------
    // 256 threads * float4 = 1024 floats = C exactly; thread tid owns column-4 tid.
    float4* out4 = reinterpret_cast<float4*>(out);
    for (int tok = 0; tok < TB; ++tok) {
        const size_t base = (t0 + tok) * K4;
        const float4 xs0 = x4[base + 0 * 256 + tid];
        const float4 xs1 = x4[base + 1 * 256 + tid];
        const float4 xs2 = x4[base + 2 * 256 + tid];
        const float4 xs3 = x4[base + 3 * 256 + tid];
        const float hp0 = s_Hpre[tok][0];
        const float hp1 = s_Hpre[tok][1];
        const float hp2 = s_Hpre[tok][2];
        const float hp3 = s_Hpre[tok][3];
        float4 xp;
        xp.x = fmaf(hp0, xs0.x, fmaf(hp1, xs1.x, fmaf(hp2, xs2.x, hp3 * xs3.x)));
        xp.y = fmaf(hp0, xs0.y, fmaf(hp1, xs1.y, fmaf(hp2, xs2.y, hp3 * xs3.y)));
        xp.z = fmaf(hp0, xs0.z, fmaf(hp1, xs1.z, fmaf(hp2, xs2.z, hp3 * xs3.z)));
        xp.w = fmaf(hp0, xs0.w, fmaf(hp1, xs1.w, fmaf(hp2, xs2.w, hp3 * xs3.w)));
#pragma unroll
        for (int i2 = 0; i2 < 4; ++i2) {
            const float h0 = s_Hres[tok][i2][0];
            const float h1 = s_Hres[tok][i2][1];
            const float h2 = s_Hres[tok][i2][2];
            const float h3 = s_Hres[tok][i2][3];
            const float hq = s_Hpost[tok][i2];
            float4 o;
            o.x = fmaf(h0, xs0.x, fmaf(h1, xs1.x, fmaf(h2, xs2.x, fmaf(h3, xs3.x, hq * xp.x))));
            o.y = fmaf(h0, xs0.y, fmaf(h1, xs1.y, fmaf(h2, xs2.y, fmaf(h3, xs3.y, hq * xp.y))));
            o.z = fmaf(h0, xs0.z, fmaf(h1, xs1.z, fmaf(h2, xs2.z, fmaf(h3, xs3.z, hq * xp.z))));
            o.w = fmaf(h0, xs0.w, fmaf(h1, xs1.w, fmaf(h2, xs2.w, fmaf(h3, xs3.w, hq * xp.w))));
            out4[base + i2 * 256 + tid] = o;
        }
    }
}

extern "C" void kernel_launch(void* const* d_in, const int* in_sizes, int n_in,
                              void* d_out, int out_size, void* d_ws, size_t ws_size,
                              hipStream_t stream) {
    const float* x       = (const float*)d_in[0];
    const float* Wres    = (const float*)d_in[1];
    const float* Wpre    = (const float*)d_in[2];
    const float* Wpost   = (const float*)d_in[3];
    const float* Hres_b  = (const float*)d_in[4];
    const float* Hpre_b  = (const float*)d_in[5];
    const float* Hpost_b = (const float*)d_in[6];
    const float* gate    = (const float*)d_in[7];
    float* out = (float*)d_out;

    const int tokens = in_sizes[0] / KDIM;   // 16384
    const int grid   = tokens / TB;          // 2048
    hipLaunchKernelGGL(dynmhc_fused, dim3(grid), dim3(256), 0, stream,
                       x, Wres, Wpre, Wpost, Hres_b, Hpre_b, Hpost_b, gate, out);
}